// Round 2
// baseline (422.862 us; speedup 1.0000x reference)
//
#include <hip/hip_runtime.h>
#include <math.h>

#define NQ   12
#define NL   4
#define DIM  4096          // 2^NQ
#define BLK  256
#define APT  16            // amplitudes per thread

// Swizzled LDS word address of amplitude i's real part; imag at +1.
// Interleaved layout: amp i -> words 2i, 2i+1; XOR-swizzle on 4-word chunks
// (bank bits 2..4 ^= chunk bits 3..5) keeps float4/float2 alignment intact.
__device__ __forceinline__ int ampw(int i) {
    int wi = i << 1;
    return wi ^ (((wi >> 5) & 7) << 2);
}

// Ga = (u00r,u00i,u01r,u01i), Gb = (u10r,u10i,u11r,u11i) from enclosing scope
#define CGATE(AR, AI, R0, R1)                                        \
  { const float a0r = AR[R0], a0i = AI[R0];                          \
    const float a1r = AR[R1], a1i = AI[R1];                          \
    AR[R0] = Ga.x*a0r - Ga.y*a0i + Ga.z*a1r - Ga.w*a1i;              \
    AI[R0] = Ga.x*a0i + Ga.y*a0r + Ga.z*a1i + Ga.w*a1r;              \
    AR[R1] = Gb.x*a0r - Gb.y*a0i + Gb.z*a1r - Gb.w*a1i;              \
    AI[R1] = Gb.x*a0i + Gb.y*a0r + Gb.z*a1i + Gb.w*a1r; }

__global__ __launch_bounds__(BLK, 4) void qsim_kernel(
    const float* __restrict__ x,     // (B, 12)
    const float* __restrict__ qw,    // (144,)
    const float* __restrict__ dw,    // (12, 12)
    const float* __restrict__ db,    // (12,)
    float* __restrict__ out)         // (B, 12)
{
    __shared__ __align__(16) float sh[2 * DIM];     // interleaved re/im, swizzled
    __shared__ __align__(16) float g[NL * NQ * 8];  // fused RZ*RY*RX per (layer,qubit)
    __shared__ float xv[NQ], enc_c[NQ], enc_s[NQ];
    __shared__ float red[64];

    const int tid  = threadIdx.x;
    const int lane = tid & 63;
    const int wv   = tid >> 6;
    const int s    = blockIdx.x;

    // ---- fused variational gate matrices (threads 0..47) ----
    if (tid < NL * NQ) {
        int l = tid / NQ, q = tid % NQ;
        int p = l * 3 * NQ + 3 * q;
        float t1 = qw[p], t2 = qw[p + 1], t3 = qw[p + 2];
        float a, b, c, d, gr, h;
        sincosf(0.5f * t1, &b, &a);   // RX
        sincosf(0.5f * t2, &d, &c);   // RY
        sincosf(0.5f * t3, &h, &gr);  // RZ
        float m00r =  c * a, m00i =  d * b;
        float m01r = -d * a, m01i = -c * b;
        float m10r =  d * a, m10i = -c * b;
        float m11r =  c * a, m11i = -d * b;
        float* G = &g[tid * 8];
        G[0] = gr * m00r + h * m00i;  G[1] = gr * m00i - h * m00r;
        G[2] = gr * m01r + h * m01i;  G[3] = gr * m01i - h * m01r;
        G[4] = gr * m10r - h * m10i;  G[5] = gr * m10i + h * m10r;
        G[6] = gr * m11r - h * m11i;  G[7] = gr * m11i + h * m11r;
    }
    if (tid < NQ) xv[tid] = x[s * NQ + tid];
    __syncthreads();
    if (tid < NQ) {
        float ss = 0.f;
        #pragma unroll
        for (int j = 0; j < NQ; ++j) ss += xv[j] * xv[j];
        float inv = rsqrtf(fmaxf(ss, 1e-12f));
        float mx = 0.f;
        #pragma unroll
        for (int j = 0; j < NQ; ++j) mx = fmaxf(mx, fabsf(xv[j] * inv));
        float ang = 3.14159265358979323846f * (xv[tid] * inv) / (mx + 1e-8f);
        float cc, sn;
        sincosf(0.5f * ang, &sn, &cc);
        enc_c[tid] = cc; enc_s[tid] = sn;
    }
    __syncthreads();

    // ---- product-state init directly into registers ----
    // amp index i = (tid<<4)|r; bit j of i <-> wire (11-j)
    float ar[APT], ai[APT];
    {
        float prefix = 1.f;
        #pragma unroll
        for (int w = 0; w < 8; ++w)          // wires 0..7 from tid bits 7..0
            prefix *= ((tid >> (7 - w)) & 1) ? enc_s[w] : enc_c[w];
        float u4[4], v4[4];
        #pragma unroll
        for (int k = 0; k < 4; ++k) {        // wires 8,9 = r bits 3,2; wires 10,11 = r bits 1,0
            u4[k] = ((k & 2) ? enc_s[8]  : enc_c[8])  * ((k & 1) ? enc_s[9]  : enc_c[9]);
            v4[k] = ((k & 2) ? enc_s[10] : enc_c[10]) * ((k & 1) ? enc_s[11] : enc_c[11]);
        }
        #pragma unroll
        for (int r = 0; r < APT; ++r) {
            ar[r] = prefix * u4[r >> 2] * v4[r & 3];
            ai[r] = 0.f;
        }
    }

    // ---- CNOT-ring permutation, pre-swizzled addresses (same every layer) ----
    int sigw[APT];
    #pragma unroll
    for (int r = 0; r < APT; ++r) {
        int j = (tid << 4) | r;
        #pragma unroll
        for (int c = NQ - 1; c >= 0; --c) {
            int t = (c + 1) % NQ;
            int cb = (j >> (NQ - 1 - c)) & 1;
            j ^= cb << (NQ - 1 - t);
        }
        sigw[r] = ampw(j);
    }

    // ---- variational layers ----
    for (int l = 0; l < NL; ++l) {
        const float* GL = &g[l * NQ * 8];

        // (1) register gates: bits 0..3 = wires 11,10,9,8 — pure FMA
        #pragma unroll
        for (int j = 0; j < 4; ++j) {
            const float* G = &GL[(11 - j) * 8];
            const float4 Ga = *(const float4*)G;
            const float4 Gb = *(const float4*)(G + 4);
            #pragma unroll
            for (int h = 0; h < 8; ++h) {
                const int r0 = ((h >> j) << (j + 1)) | (h & ((1 << j) - 1));
                const int r1 = r0 | (1 << j);
                CGATE(ar, ai, r0, r1);
            }
        }

        // (2) lane gates: bits 4..9 = wires 7..2 — shfl_xor, no sync
        #pragma unroll
        for (int j = 4; j <= 9; ++j) {
            const float* G = &GL[(11 - j) * 8];
            const float4 Ga = *(const float4*)G;
            const float4 Gb = *(const float4*)(G + 4);
            const int m = 1 << (j - 4);
            const bool hi = (lane & m) != 0;
            const float cor = hi ? Gb.z : Ga.x;   // c_own
            const float coi = hi ? Gb.w : Ga.y;
            const float ctr = hi ? Gb.x : Ga.z;   // c_other
            const float cti = hi ? Gb.y : Ga.w;
            #pragma unroll
            for (int r = 0; r < APT; ++r) {
                const float orr = __shfl_xor(ar[r], m);
                const float oii = __shfl_xor(ai[r], m);
                const float nr = cor * ar[r] - coi * ai[r] + ctr * orr - cti * oii;
                const float ni = cor * ai[r] + coi * ar[r] + ctr * oii + cti * orr;
                ar[r] = nr; ai[r] = ni;
            }
        }

        // (3) stage to LDS (swizzled, conflict-free b128)
        #pragma unroll
        for (int k = 0; k < 8; ++k) {
            const int w4 = ampw((tid << 4) | (k << 1));
            *(float4*)&sh[w4] = make_float4(ar[2 * k], ai[2 * k], ar[2 * k + 1], ai[2 * k + 1]);
        }
        __syncthreads();

        // (4) phase B: re-own so bits 11,10 (wires 0,1) are register bits
        float br[APT], bi[APT];
        #pragma unroll
        for (int hb = 0; hb < 4; ++hb) {
            #pragma unroll
            for (int h = 0; h < 2; ++h) {
                const int i0 = (hb << 10) | (lane << 4) | (wv << 2) | (h << 1);
                const float4 v = *(const float4*)&sh[ampw(i0)];
                br[(hb << 2) | (h << 1)]     = v.x;
                bi[(hb << 2) | (h << 1)]     = v.y;
                br[(hb << 2) | (h << 1) | 1] = v.z;
                bi[(hb << 2) | (h << 1) | 1] = v.w;
            }
        }
        {   // wire 0 gate on br-index bit 3
            const float* G = &GL[0 * 8];
            const float4 Ga = *(const float4*)G;
            const float4 Gb = *(const float4*)(G + 4);
            #pragma unroll
            for (int p = 0; p < 8; ++p) CGATE(br, bi, p, p + 8);
        }
        {   // wire 1 gate on br-index bit 2
            const float* G = &GL[1 * 8];
            const float4 Ga = *(const float4*)G;
            const float4 Gb = *(const float4*)(G + 4);
            #pragma unroll
            for (int h = 0; h < 8; ++h) {
                const int p = ((h >> 2) << 3) | (h & 3);
                CGATE(br, bi, p, p + 4);
            }
        }
        #pragma unroll
        for (int hb = 0; hb < 4; ++hb) {   // write back to the same addresses (no hazard)
            #pragma unroll
            for (int h = 0; h < 2; ++h) {
                const int i0 = (hb << 10) | (lane << 4) | (wv << 2) | (h << 1);
                const int b0 = (hb << 2) | (h << 1);
                *(float4*)&sh[ampw(i0)] = make_float4(br[b0], bi[b0], br[b0 + 1], bi[b0 + 1]);
            }
        }
        __syncthreads();

        // (5) CNOT-ring permutation gather back into canonical registers
        #pragma unroll
        for (int r = 0; r < APT; ++r) {
            const float2 v = *(const float2*)&sh[sigw[r]];
            ar[r] = v.x; ai[r] = v.y;
        }
        __syncthreads();
    }

    // ---- Z expectations ----
    float S = 0.f, a8 = 0.f, a9 = 0.f, a10 = 0.f, a11 = 0.f;
    #pragma unroll
    for (int r = 0; r < APT; ++r) {
        const float pr = ar[r] * ar[r] + ai[r] * ai[r];
        S += pr;
        a8  += (r & 8) ? -pr : pr;   // wire 8  = r bit 3
        a9  += (r & 4) ? -pr : pr;   // wire 9  = r bit 2
        a10 += (r & 2) ? -pr : pr;   // wire 10 = r bit 1
        a11 += (r & 1) ? -pr : pr;   // wire 11 = r bit 0
    }
    float vals[NQ];
    #pragma unroll
    for (int w = 0; w < 8; ++w)
        vals[w] = ((tid >> (7 - w)) & 1) ? -S : S;
    vals[8] = a8; vals[9] = a9; vals[10] = a10; vals[11] = a11;
    #pragma unroll
    for (int m = 1; m <= 32; m <<= 1) {
        #pragma unroll
        for (int w = 0; w < NQ; ++w) vals[w] += __shfl_xor(vals[w], m);
    }
    if (lane == 0) {
        #pragma unroll
        for (int w = 0; w < NQ; ++w) red[wv * NQ + w] = vals[w];
    }
    __syncthreads();
    if (tid < NQ)
        red[48 + tid] = red[tid] + red[NQ + tid] + red[2 * NQ + tid] + red[3 * NQ + tid];
    __syncthreads();
    if (tid < NQ) {
        float v = db[tid];
        #pragma unroll
        for (int w = 0; w < NQ; ++w) v += red[48 + w] * dw[w * NQ + tid];
        out[s * NQ + tid] = tanhf(v);
    }
}

extern "C" void kernel_launch(void* const* d_in, const int* in_sizes, int n_in,
                              void* d_out, int out_size, void* d_ws, size_t ws_size,
                              hipStream_t stream) {
    const float* x  = (const float*)d_in[0];
    const float* qw = (const float*)d_in[1];
    const float* dw = (const float*)d_in[2];
    const float* db = (const float*)d_in[3];
    float* out = (float*)d_out;
    int batch = in_sizes[0] / NQ;
    qsim_kernel<<<batch, BLK, 0, stream>>>(x, qw, dw, db, out);
}

// Round 3
// 373.246 us; speedup vs baseline: 1.1329x; 1.1329x over previous
//
#include <hip/hip_runtime.h>
#include <math.h>

#define NQ   12
#define NL   4
#define DIM  4096          // 2^NQ
#define BLK  256
#define APT  16            // amplitudes per thread

// Swizzled LDS word address of amplitude i's real part; imag at +1.
// Interleaved layout: amp i -> words 2i, 2i+1; XOR-swizzle on 4-word chunks.
// GF(2)-linear: ampw_c(a^b) == ampw_c(a)^ampw_c(b).
__device__ __forceinline__ constexpr int ampw_c(int i) {
    int wi = i << 1;
    return wi ^ (((wi >> 5) & 7) << 2);
}

// CNOT-ring basis-state permutation (gather map): final[i] = pre[sigma_c(i)].
// Composition of bit-XOR steps => GF(2)-linear, sigma_c(0)=0.
__device__ __forceinline__ constexpr int sigma_c(int i) {
    int j = i;
    for (int c = NQ - 1; c >= 0; --c) {
        int t = (c + 1) % NQ;
        int cb = (j >> (NQ - 1 - c)) & 1;
        j ^= cb << (NQ - 1 - t);
    }
    return j;
}

// Ga = (u00r,u00i,u01r,u01i), Gb = (u10r,u10i,u11r,u11i) from enclosing scope
#define CGATE(AR, AI, R0, R1)                                        \
  { const float a0r = AR[R0], a0i = AI[R0];                          \
    const float a1r = AR[R1], a1i = AI[R1];                          \
    AR[R0] = Ga.x*a0r - Ga.y*a0i + Ga.z*a1r - Ga.w*a1i;              \
    AI[R0] = Ga.x*a0i + Ga.y*a0r + Ga.z*a1i + Ga.w*a1r;              \
    AR[R1] = Gb.x*a0r - Gb.y*a0i + Gb.z*a1r - Gb.w*a1i;              \
    AI[R1] = Gb.x*a0i + Gb.y*a0r + Gb.z*a1i + Gb.w*a1r; }

__global__ __launch_bounds__(BLK) void qsim_kernel(
    const float* __restrict__ x,     // (B, 12)
    const float* __restrict__ qw,    // (144,)
    const float* __restrict__ dw,    // (12, 12)
    const float* __restrict__ db,    // (12,)
    float* __restrict__ out)         // (B, 12)
{
    __shared__ __align__(16) float sh[2 * DIM];     // interleaved re/im, swizzled
    __shared__ __align__(16) float g[NL * NQ * 8];  // fused RZ*RY*RX per (layer,qubit)
    __shared__ float xv[NQ], enc_c[NQ], enc_s[NQ];
    __shared__ float red[64];

    const int tid  = threadIdx.x;
    const int lane = tid & 63;
    const int wv   = tid >> 6;
    const int s    = blockIdx.x;

    // ---- fused variational gate matrices (threads 0..47) ----
    if (tid < NL * NQ) {
        int l = tid / NQ, q = tid % NQ;
        int p = l * 3 * NQ + 3 * q;
        float t1 = qw[p], t2 = qw[p + 1], t3 = qw[p + 2];
        float a, b, c, d, gr, h;
        sincosf(0.5f * t1, &b, &a);   // RX
        sincosf(0.5f * t2, &d, &c);   // RY
        sincosf(0.5f * t3, &h, &gr);  // RZ
        float m00r =  c * a, m00i =  d * b;
        float m01r = -d * a, m01i = -c * b;
        float m10r =  d * a, m10i = -c * b;
        float m11r =  c * a, m11i = -d * b;
        float* G = &g[tid * 8];
        G[0] = gr * m00r + h * m00i;  G[1] = gr * m00i - h * m00r;
        G[2] = gr * m01r + h * m01i;  G[3] = gr * m01i - h * m01r;
        G[4] = gr * m10r - h * m10i;  G[5] = gr * m10i + h * m10r;
        G[6] = gr * m11r - h * m11i;  G[7] = gr * m11i + h * m11r;
    }
    if (tid < NQ) xv[tid] = x[s * NQ + tid];
    __syncthreads();
    if (tid < NQ) {
        float ss = 0.f;
        #pragma unroll
        for (int j = 0; j < NQ; ++j) ss += xv[j] * xv[j];
        float inv = rsqrtf(fmaxf(ss, 1e-12f));
        float mx = 0.f;
        #pragma unroll
        for (int j = 0; j < NQ; ++j) mx = fmaxf(mx, fabsf(xv[j] * inv));
        float ang = 3.14159265358979323846f * (xv[tid] * inv) / (mx + 1e-8f);
        float cc, sn;
        sincosf(0.5f * ang, &sn, &cc);
        enc_c[tid] = cc; enc_s[tid] = sn;
    }
    __syncthreads();

    // ---- product-state init directly into registers ----
    // amp index i = (tid<<4)|r; bit j of i <-> wire (11-j)
    float ar[APT], ai[APT];
    {
        float prefix = 1.f;
        #pragma unroll
        for (int w = 0; w < 8; ++w)
            prefix *= ((tid >> (7 - w)) & 1) ? enc_s[w] : enc_c[w];
        float u4[4], v4[4];
        #pragma unroll
        for (int k = 0; k < 4; ++k) {
            u4[k] = ((k & 2) ? enc_s[8]  : enc_c[8])  * ((k & 1) ? enc_s[9]  : enc_c[9]);
            v4[k] = ((k & 2) ? enc_s[10] : enc_c[10]) * ((k & 1) ? enc_s[11] : enc_c[11]);
        }
        #pragma unroll
        for (int r = 0; r < APT; ++r) {
            ar[r] = prefix * u4[r >> 2] * v4[r & 3];
            ai[r] = 0.f;
        }
    }

    // Per-thread base of the swizzled permutation address; per-r offset is a
    // compile-time constant XOR (both maps GF(2)-linear, disjoint bit fields).
    const int wbase = ampw_c(sigma_c(tid << 4));

    // ---- variational layers ----
    for (int l = 0; l < NL; ++l) {
        const float* GL = &g[l * NQ * 8];

        // (1) register gates: bits 0..3 = wires 11,10,9,8 — pure FMA
        #pragma unroll
        for (int j = 0; j < 4; ++j) {
            const float* G = &GL[(11 - j) * 8];
            const float4 Ga = *(const float4*)G;
            const float4 Gb = *(const float4*)(G + 4);
            #pragma unroll
            for (int h = 0; h < 8; ++h) {
                const int r0 = ((h >> j) << (j + 1)) | (h & ((1 << j) - 1));
                const int r1 = r0 | (1 << j);
                CGATE(ar, ai, r0, r1);
            }
        }

        // (2) lane gates: bits 4..9 = wires 7..2 — shfl_xor, no sync
        #pragma unroll
        for (int j = 4; j <= 9; ++j) {
            const float* G = &GL[(11 - j) * 8];
            const float4 Ga = *(const float4*)G;
            const float4 Gb = *(const float4*)(G + 4);
            const int m = 1 << (j - 4);
            const bool hi = (lane & m) != 0;
            const float cor = hi ? Gb.z : Ga.x;   // own coeff
            const float coi = hi ? Gb.w : Ga.y;
            const float ctr = hi ? Gb.x : Ga.z;   // partner coeff
            const float cti = hi ? Gb.y : Ga.w;
            #pragma unroll
            for (int r = 0; r < APT; ++r) {
                const float orr = __shfl_xor(ar[r], m);
                const float oii = __shfl_xor(ai[r], m);
                const float nr = cor * ar[r] - coi * ai[r] + ctr * orr - cti * oii;
                const float ni = cor * ai[r] + coi * ar[r] + ctr * oii + cti * orr;
                ar[r] = nr; ai[r] = ni;
            }
        }

        // (3) stage to LDS (swizzled, conflict-free b128)
        #pragma unroll
        for (int k = 0; k < 8; ++k) {
            const int w4 = ampw_c((tid << 4) | (k << 1));
            *(float4*)&sh[w4] = make_float4(ar[2 * k], ai[2 * k], ar[2 * k + 1], ai[2 * k + 1]);
        }
        __syncthreads();

        // (4) phase B: re-own so bits 11,10 (wires 0,1) are register bits.
        // Reuses ar/ai (dead across the LDS round trip) to cap live VGPRs.
        #pragma unroll
        for (int hb = 0; hb < 4; ++hb) {
            #pragma unroll
            for (int h = 0; h < 2; ++h) {
                const int i0 = (hb << 10) | (lane << 4) | (wv << 2) | (h << 1);
                const float4 v = *(const float4*)&sh[ampw_c(i0)];
                ar[(hb << 2) | (h << 1)]     = v.x;
                ai[(hb << 2) | (h << 1)]     = v.y;
                ar[(hb << 2) | (h << 1) | 1] = v.z;
                ai[(hb << 2) | (h << 1) | 1] = v.w;
            }
        }
        {   // wire 0 gate on index bit 3
            const float* G = &GL[0 * 8];
            const float4 Ga = *(const float4*)G;
            const float4 Gb = *(const float4*)(G + 4);
            #pragma unroll
            for (int p = 0; p < 8; ++p) CGATE(ar, ai, p, p + 8);
        }
        {   // wire 1 gate on index bit 2
            const float* G = &GL[1 * 8];
            const float4 Ga = *(const float4*)G;
            const float4 Gb = *(const float4*)(G + 4);
            #pragma unroll
            for (int h = 0; h < 8; ++h) {
                const int p = ((h >> 2) << 3) | (h & 3);
                CGATE(ar, ai, p, p + 4);
            }
        }
        #pragma unroll
        for (int hb = 0; hb < 4; ++hb) {   // write back to same addresses (disjoint ownership)
            #pragma unroll
            for (int h = 0; h < 2; ++h) {
                const int i0 = (hb << 10) | (lane << 4) | (wv << 2) | (h << 1);
                const int b0 = (hb << 2) | (h << 1);
                *(float4*)&sh[ampw_c(i0)] = make_float4(ar[b0], ai[b0], ar[b0 + 1], ai[b0 + 1]);
            }
        }
        __syncthreads();

        // (5) CNOT-ring permutation gather back into canonical registers:
        // address = wbase ^ compile-time constant (no sigw array).
        #pragma unroll
        for (int r = 0; r < APT; ++r) {
            const float2 v = *(const float2*)&sh[wbase ^ ampw_c(sigma_c(r))];
            ar[r] = v.x; ai[r] = v.y;
        }
        __syncthreads();
    }

    // ---- Z expectations ----
    float S = 0.f, a8 = 0.f, a9 = 0.f, a10 = 0.f, a11 = 0.f;
    #pragma unroll
    for (int r = 0; r < APT; ++r) {
        const float pr = ar[r] * ar[r] + ai[r] * ai[r];
        S += pr;
        a8  += (r & 8) ? -pr : pr;
        a9  += (r & 4) ? -pr : pr;
        a10 += (r & 2) ? -pr : pr;
        a11 += (r & 1) ? -pr : pr;
    }
    float vals[NQ];
    #pragma unroll
    for (int w = 0; w < 8; ++w)
        vals[w] = ((tid >> (7 - w)) & 1) ? -S : S;
    vals[8] = a8; vals[9] = a9; vals[10] = a10; vals[11] = a11;
    #pragma unroll
    for (int m = 1; m <= 32; m <<= 1) {
        #pragma unroll
        for (int w = 0; w < NQ; ++w) vals[w] += __shfl_xor(vals[w], m);
    }
    if (lane == 0) {
        #pragma unroll
        for (int w = 0; w < NQ; ++w) red[wv * NQ + w] = vals[w];
    }
    __syncthreads();
    if (tid < NQ)
        red[48 + tid] = red[tid] + red[NQ + tid] + red[2 * NQ + tid] + red[3 * NQ + tid];
    __syncthreads();
    if (tid < NQ) {
        float v = db[tid];
        #pragma unroll
        for (int w = 0; w < NQ; ++w) v += red[48 + w] * dw[w * NQ + tid];
        out[s * NQ + tid] = tanhf(v);
    }
}

extern "C" void kernel_launch(void* const* d_in, const int* in_sizes, int n_in,
                              void* d_out, int out_size, void* d_ws, size_t ws_size,
                              hipStream_t stream) {
    const float* x  = (const float*)d_in[0];
    const float* qw = (const float*)d_in[1];
    const float* dw = (const float*)d_in[2];
    const float* db = (const float*)d_in[3];
    float* out = (float*)d_out;
    int batch = in_sizes[0] / NQ;
    qsim_kernel<<<batch, BLK, 0, stream>>>(x, qw, dw, db, out);
}

// Round 4
// 311.197 us; speedup vs baseline: 1.3588x; 1.1994x over previous
//
#include <hip/hip_runtime.h>
#include <math.h>

#define NQ   12
#define NL   4
#define DIM  4096          // 2^NQ
#define BLK  256
#define APT  16            // amplitudes per thread

// Word address of amplitude i's real part (imag at +1). Interleaved re/im,
// XOR bank swizzle f(i) = (i>>4 ^ i>>8)&7 into word bits 2..4.
// GF(2)-linear: wmix(a^b) == wmix(a)^wmix(b) for disjoint-bit a,b.
__device__ __forceinline__ constexpr int wmix(int i) {
    return (i << 1) ^ ((((i >> 4) ^ (i >> 8)) & 7) << 2);
}

// CNOT-ring basis-state permutation (gather map): final[i] = pre[sigma_c(i)].
// Composition of bit-XOR steps => GF(2)-linear, sigma_c(0)=0.
__device__ __forceinline__ constexpr int sigma_c(int i) {
    int j = i;
    for (int c = NQ - 1; c >= 0; --c) {
        int t = (c + 1) % NQ;
        int cb = (j >> (NQ - 1 - c)) & 1;
        j ^= cb << (NQ - 1 - t);
    }
    return j;
}

// Ga = (u00r,u00i,u01r,u01i), Gb = (u10r,u10i,u11r,u11i) from enclosing scope
#define CGATE(AR, AI, R0, R1)                                        \
  { const float a0r = AR[R0], a0i = AI[R0];                          \
    const float a1r = AR[R1], a1i = AI[R1];                          \
    AR[R0] = Ga.x*a0r - Ga.y*a0i + Ga.z*a1r - Ga.w*a1i;              \
    AI[R0] = Ga.x*a0i + Ga.y*a0r + Ga.z*a1i + Ga.w*a1r;              \
    AR[R1] = Gb.x*a0r - Gb.y*a0i + Gb.z*a1r - Gb.w*a1i;              \
    AI[R1] = Gb.x*a0i + Gb.y*a0r + Gb.z*a1i + Gb.w*a1r; }

// Apply 4 gates on register-index bits 3..0; bit j corresponds to wire WB+3-j.
#define APPLY4(GL, WB)                                               \
  { _Pragma("unroll")                                                \
    for (int j = 0; j < 4; ++j) {                                    \
      const float* G = &(GL)[((WB) + 3 - j) * 8];                    \
      const float4 Ga = *(const float4*)G;                           \
      const float4 Gb = *(const float4*)(G + 4);                     \
      _Pragma("unroll")                                              \
      for (int h = 0; h < 8; ++h) {                                  \
        const int r0 = ((h >> j) << (j + 1)) | (h & ((1 << j) - 1)); \
        const int r1 = r0 | (1 << j);                                \
        CGATE(ar, ai, r0, r1);                                       \
      }                                                              \
    } }

__global__ __launch_bounds__(BLK) void qsim_kernel(
    const float* __restrict__ x,     // (B, 12)
    const float* __restrict__ qw,    // (144,)
    const float* __restrict__ dw,    // (12, 12)
    const float* __restrict__ db,    // (12,)
    float* __restrict__ out)         // (B, 12)
{
    __shared__ __align__(16) float sh[2 * DIM];     // interleaved re/im, swizzled
    __shared__ __align__(16) float g[NL * NQ * 8];  // fused RZ*RY*RX per (layer,qubit)
    __shared__ float xv[NQ], enc_c[NQ], enc_s[NQ];
    __shared__ float red[64];

    const int tid  = threadIdx.x;
    const int lane = tid & 63;
    const int wv   = tid >> 6;
    const int s    = blockIdx.x;

    // ---- fused variational gate matrices (threads 0..47) ----
    if (tid < NL * NQ) {
        int l = tid / NQ, q = tid % NQ;
        int p = l * 3 * NQ + 3 * q;
        float t1 = qw[p], t2 = qw[p + 1], t3 = qw[p + 2];
        float a, b, c, d, gr, h;
        sincosf(0.5f * t1, &b, &a);   // RX
        sincosf(0.5f * t2, &d, &c);   // RY
        sincosf(0.5f * t3, &h, &gr);  // RZ
        float m00r =  c * a, m00i =  d * b;
        float m01r = -d * a, m01i = -c * b;
        float m10r =  d * a, m10i = -c * b;
        float m11r =  c * a, m11i = -d * b;
        float* G = &g[tid * 8];
        G[0] = gr * m00r + h * m00i;  G[1] = gr * m00i - h * m00r;
        G[2] = gr * m01r + h * m01i;  G[3] = gr * m01i - h * m01r;
        G[4] = gr * m10r - h * m10i;  G[5] = gr * m10i + h * m10r;
        G[6] = gr * m11r - h * m11i;  G[7] = gr * m11i + h * m11r;
    }
    if (tid < NQ) xv[tid] = x[s * NQ + tid];
    __syncthreads();
    if (tid < NQ) {
        float ss = 0.f;
        #pragma unroll
        for (int j = 0; j < NQ; ++j) ss += xv[j] * xv[j];
        float inv = rsqrtf(fmaxf(ss, 1e-12f));
        float mx = 0.f;
        #pragma unroll
        for (int j = 0; j < NQ; ++j) mx = fmaxf(mx, fabsf(xv[j] * inv));
        float ang = 3.14159265358979323846f * (xv[tid] * inv) / (mx + 1e-8f);
        float cc, sn;
        sincosf(0.5f * ang, &sn, &cc);
        enc_c[tid] = cc; enc_s[tid] = sn;
    }
    __syncthreads();

    // ---- product-state init in registers (phase-1 ownership: i = (tid<<4)|r) ----
    float ar[APT], ai[APT];
    {
        float prefix = 1.f;
        #pragma unroll
        for (int w = 0; w < 8; ++w)
            prefix *= ((tid >> (7 - w)) & 1) ? enc_s[w] : enc_c[w];
        float u4[4], v4[4];
        #pragma unroll
        for (int k = 0; k < 4; ++k) {
            u4[k] = ((k & 2) ? enc_s[8]  : enc_c[8])  * ((k & 1) ? enc_s[9]  : enc_c[9]);
            v4[k] = ((k & 2) ? enc_s[10] : enc_c[10]) * ((k & 1) ? enc_s[11] : enc_c[11]);
        }
        #pragma unroll
        for (int r = 0; r < APT; ++r) {
            ar[r] = prefix * u4[r >> 2] * v4[r & 3];
            ai[r] = 0.f;
        }
    }

    // Runtime per-thread address bases; per-r offsets are compile-time XORs.
    const int a1 = wmix(tid << 4);                                  // O1: i=(tid<<4)|r
    const int a2 = wmix(((tid & 0xF0) << 4) | (tid & 0x0F));        // O2: i=th<<8|r<<4|tl
    const int a3 = wmix(tid);                                       // O3: i=(r<<8)|tid
    const int aS = wmix(sigma_c(tid << 4));                         // perm gather base

    // ---- variational layers: 12 register gates + 3 LDS round trips each ----
    for (int l = 0; l < NL; ++l) {
        const float* GL = &g[l * NQ * 8];

        APPLY4(GL, 8);                       // wires 8..11 on bits i3..i0
        #pragma unroll
        for (int k = 0; k < 8; ++k)          // W1: b128 amp pairs
            *(float4*)&sh[a1 ^ wmix(2 * k)] =
                make_float4(ar[2 * k], ai[2 * k], ar[2 * k + 1], ai[2 * k + 1]);
        __syncthreads();

        #pragma unroll
        for (int r = 0; r < APT; ++r) {      // R2: own bits i7..i4
            const float2 v = *(const float2*)&sh[a2 ^ wmix(r << 4)];
            ar[r] = v.x; ai[r] = v.y;
        }
        APPLY4(GL, 4);                       // wires 4..7
        #pragma unroll
        for (int r = 0; r < APT; ++r)        // W2: same addresses as R2
            *(float2*)&sh[a2 ^ wmix(r << 4)] = make_float2(ar[r], ai[r]);
        __syncthreads();

        #pragma unroll
        for (int r = 0; r < APT; ++r) {      // R3: own bits i11..i8
            const float2 v = *(const float2*)&sh[a3 ^ wmix(r << 8)];
            ar[r] = v.x; ai[r] = v.y;
        }
        APPLY4(GL, 0);                       // wires 0..3
        #pragma unroll
        for (int r = 0; r < APT; ++r)        // W3: same addresses as R3
            *(float2*)&sh[a3 ^ wmix(r << 8)] = make_float2(ar[r], ai[r]);
        __syncthreads();

        #pragma unroll
        for (int r = 0; r < APT; ++r) {      // Rsigma: CNOT ring, back to O1
            const float2 v = *(const float2*)&sh[aS ^ wmix(sigma_c(r))];
            ar[r] = v.x; ai[r] = v.y;
        }
        __syncthreads();                     // anti-dep before next layer's W1
    }

    // ---- Z expectations (state in O1 ownership) ----
    float S = 0.f, a8 = 0.f, a9 = 0.f, a10 = 0.f, a11 = 0.f;
    #pragma unroll
    for (int r = 0; r < APT; ++r) {
        const float pr = ar[r] * ar[r] + ai[r] * ai[r];
        S += pr;
        a8  += (r & 8) ? -pr : pr;
        a9  += (r & 4) ? -pr : pr;
        a10 += (r & 2) ? -pr : pr;
        a11 += (r & 1) ? -pr : pr;
    }
    float vals[NQ];
    #pragma unroll
    for (int w = 0; w < 8; ++w)
        vals[w] = ((tid >> (7 - w)) & 1) ? -S : S;
    vals[8] = a8; vals[9] = a9; vals[10] = a10; vals[11] = a11;
    #pragma unroll
    for (int m = 1; m <= 32; m <<= 1) {
        #pragma unroll
        for (int w = 0; w < NQ; ++w) vals[w] += __shfl_xor(vals[w], m);
    }
    if (lane == 0) {
        #pragma unroll
        for (int w = 0; w < NQ; ++w) red[wv * NQ + w] = vals[w];
    }
    __syncthreads();
    if (tid < NQ)
        red[48 + tid] = red[tid] + red[NQ + tid] + red[2 * NQ + tid] + red[3 * NQ + tid];
    __syncthreads();
    if (tid < NQ) {
        float v = db[tid];
        #pragma unroll
        for (int w = 0; w < NQ; ++w) v += red[48 + w] * dw[w * NQ + tid];
        out[s * NQ + tid] = tanhf(v);
    }
}

extern "C" void kernel_launch(void* const* d_in, const int* in_sizes, int n_in,
                              void* d_out, int out_size, void* d_ws, size_t ws_size,
                              hipStream_t stream) {
    const float* x  = (const float*)d_in[0];
    const float* qw = (const float*)d_in[1];
    const float* dw = (const float*)d_in[2];
    const float* db = (const float*)d_in[3];
    float* out = (float*)d_out;
    int batch = in_sizes[0] / NQ;
    qsim_kernel<<<batch, BLK, 0, stream>>>(x, qw, dw, db, out);
}

// Round 5
// 205.692 us; speedup vs baseline: 2.0558x; 1.5129x over previous
//
#include <hip/hip_runtime.h>
#include <math.h>

#define NQ   12
#define NL   4
#define DIM  4096          // 2^NQ
#define BLK  256
#define APT  16            // amplitudes per thread

typedef float v2f __attribute__((ext_vector_type(2)));

// Word address of amplitude i's real part (imag at +1). Interleaved re/im,
// XOR bank swizzle f(i) = (i>>4 ^ i>>8)&7 into word bits 2..4 (keeps 16B align).
// GF(2)-linear for disjoint-bit arguments.
__device__ __forceinline__ constexpr int wmix(int i) {
    return (i << 1) ^ ((((i >> 4) ^ (i >> 8)) & 7) << 2);
}

// CNOT-ring basis-state permutation (gather map): final[i] = pre[sigma_c(i)].
// Composition of bit-XOR steps => GF(2)-linear, sigma_c(0)=0.
__device__ __forceinline__ constexpr int sigma_c(int i) {
    int j = i;
    for (int c = NQ - 1; c >= 0; --c) {
        int t = (c + 1) % NQ;
        int cb = (j >> (NQ - 1 - c)) & 1;
        j ^= cb << (NQ - 1 - t);
    }
    return j;
}

// Packed-complex gate update: N0 = u00*A0 + u01*A1, N1 = u10*A0 + u11*A1.
// A~ = (-a.y, a.x) is expressible as VOP3P op_sel+neg on the consumer fma.
#define CGATE(AV, R0, R1)                                            \
  { const v2f A0 = AV[R0], A1 = AV[R1];                              \
    const v2f A0s = { -A0.y, A0.x };                                 \
    const v2f A1s = { -A1.y, A1.x };                                 \
    v2f N0 = b00r * A0;                                              \
    N0 = __builtin_elementwise_fma(b00i, A0s, N0);                   \
    N0 = __builtin_elementwise_fma(b01r, A1,  N0);                   \
    N0 = __builtin_elementwise_fma(b01i, A1s, N0);                   \
    v2f N1 = b10r * A0;                                              \
    N1 = __builtin_elementwise_fma(b10i, A0s, N1);                   \
    N1 = __builtin_elementwise_fma(b11r, A1,  N1);                   \
    N1 = __builtin_elementwise_fma(b11i, A1s, N1);                   \
    AV[R0] = N0; AV[R1] = N1; }

// Apply 4 gates on register-index bits 3..0; bit j corresponds to wire WB+3-j.
// Gates come from global memory (wave-uniform address -> scalar/L1 path).
#define APPLY4(LB, WB)                                               \
  { _Pragma("unroll")                                                \
    for (int j = 0; j < 4; ++j) {                                    \
      const float4 Ga = gg[((LB) + (WB) + 3 - j) * 2];               \
      const float4 Gb = gg[((LB) + (WB) + 3 - j) * 2 + 1];           \
      const v2f b00r = {Ga.x, Ga.x}, b00i = {Ga.y, Ga.y};            \
      const v2f b01r = {Ga.z, Ga.z}, b01i = {Ga.w, Ga.w};            \
      const v2f b10r = {Gb.x, Gb.x}, b10i = {Gb.y, Gb.y};            \
      const v2f b11r = {Gb.z, Gb.z}, b11i = {Gb.w, Gb.w};            \
      _Pragma("unroll")                                              \
      for (int h = 0; h < 8; ++h) {                                  \
        const int r0 = ((h >> j) << (j + 1)) | (h & ((1 << j) - 1)); \
        CGATE(av, r0, r0 | (1 << j));                                \
      }                                                              \
    } }

// ---- pre-kernel: fuse RZ*RY*RX per (layer,qubit) into d_ws (48 x 8 floats) ----
__global__ __launch_bounds__(64) void gate_kernel(
    const float* __restrict__ qw, float* __restrict__ gout)
{
    const int t = threadIdx.x;
    if (t < NL * NQ) {
        const int p = (t / NQ) * 3 * NQ + 3 * (t % NQ);
        float t1 = qw[p], t2 = qw[p + 1], t3 = qw[p + 2];
        float a, b, c, d, gr, h;
        sincosf(0.5f * t1, &b, &a);   // RX
        sincosf(0.5f * t2, &d, &c);   // RY
        sincosf(0.5f * t3, &h, &gr);  // RZ
        float m00r =  c * a, m00i =  d * b;
        float m01r = -d * a, m01i = -c * b;
        float m10r =  d * a, m10i = -c * b;
        float m11r =  c * a, m11i = -d * b;
        float* G = &gout[t * 8];
        G[0] = gr * m00r + h * m00i;  G[1] = gr * m00i - h * m00r;
        G[2] = gr * m01r + h * m01i;  G[3] = gr * m01i - h * m01r;
        G[4] = gr * m10r - h * m10i;  G[5] = gr * m10i + h * m10r;
        G[6] = gr * m11r - h * m11i;  G[7] = gr * m11i + h * m11r;
    }
}

__global__ __launch_bounds__(BLK) void qsim_kernel(
    const float* __restrict__ x,      // (B, 12)
    const float* __restrict__ gates,  // (48*8,) fused gate matrices from d_ws
    const float* __restrict__ dw,     // (12, 12)
    const float* __restrict__ db,     // (12,)
    float* __restrict__ out)          // (B, 12)
{
    __shared__ __align__(16) float sh[2 * DIM];   // 32768 B total (5 blocks/CU)
    // aliased scratch inside sh (live only before first W1 / after last Rsigma):
    float* xv    = sh;        // [0..11]
    float* enc_c = sh + 16;   // [16..27]
    float* enc_s = sh + 32;   // [32..43]
    float* red   = sh;        // [0..63], after final gather

    const int tid  = threadIdx.x;
    const int lane = tid & 63;
    const int wv   = tid >> 6;
    const int s    = blockIdx.x;
    const float4* __restrict__ gg = (const float4*)gates;

    if (tid < NQ) xv[tid] = x[s * NQ + tid];
    __syncthreads();
    if (tid < NQ) {
        float ss = 0.f;
        #pragma unroll
        for (int j = 0; j < NQ; ++j) ss += xv[j] * xv[j];
        float inv = rsqrtf(fmaxf(ss, 1e-12f));
        float mx = 0.f;
        #pragma unroll
        for (int j = 0; j < NQ; ++j) mx = fmaxf(mx, fabsf(xv[j] * inv));
        float ang = 3.14159265358979323846f * (xv[tid] * inv) / (mx + 1e-8f);
        float cc, sn;
        sincosf(0.5f * ang, &sn, &cc);
        enc_c[tid] = cc; enc_s[tid] = sn;
    }
    __syncthreads();

    // ---- product-state init in registers (O1 ownership: i = (tid<<4)|r) ----
    v2f av[APT];
    {
        float prefix = 1.f;
        #pragma unroll
        for (int w = 0; w < 8; ++w)
            prefix *= ((tid >> (7 - w)) & 1) ? enc_s[w] : enc_c[w];
        float u4[4], v4[4];
        #pragma unroll
        for (int k = 0; k < 4; ++k) {
            u4[k] = ((k & 2) ? enc_s[8]  : enc_c[8])  * ((k & 1) ? enc_s[9]  : enc_c[9]);
            v4[k] = ((k & 2) ? enc_s[10] : enc_c[10]) * ((k & 1) ? enc_s[11] : enc_c[11]);
        }
        #pragma unroll
        for (int r = 0; r < APT; ++r)
            av[r] = (v2f){ prefix * u4[r >> 2] * v4[r & 3], 0.f };
    }
    __syncthreads();   // enc reads done before W1 overwrites the alias region

    // Runtime per-thread address bases; per-r offsets are compile-time XORs.
    const int a1 = wmix(tid << 4);                                  // O1: i=(tid<<4)|r
    const int a2 = wmix(((tid & 0xF0) << 4) | (tid & 0x0F));        // O2: i=th<<8|r<<4|tl
    const int a3 = wmix(tid);                                       // O3: i=(r<<8)|tid
    const int aS = wmix(sigma_c(tid << 4));                         // perm gather base

    // ---- variational layers: 12 register gates + 3 LDS round trips each ----
    for (int l = 0; l < NL; ++l) {
        const int LB = l * NQ;

        APPLY4(LB, 8);                       // wires 8..11 on bits i3..i0
        #pragma unroll
        for (int k = 0; k < 8; ++k)          // W1: b128 amp pairs
            *(float4*)&sh[a1 ^ wmix(2 * k)] =
                make_float4(av[2 * k].x, av[2 * k].y, av[2 * k + 1].x, av[2 * k + 1].y);
        __syncthreads();

        #pragma unroll
        for (int r = 0; r < APT; ++r)        // R2: own bits i7..i4
            av[r] = *(const v2f*)&sh[a2 ^ wmix(r << 4)];
        APPLY4(LB, 4);                       // wires 4..7
        #pragma unroll
        for (int r = 0; r < APT; ++r)        // W2: same addresses as R2
            *(v2f*)&sh[a2 ^ wmix(r << 4)] = av[r];
        __syncthreads();

        #pragma unroll
        for (int r = 0; r < APT; ++r)        // R3: own bits i11..i8
            av[r] = *(const v2f*)&sh[a3 ^ wmix(r << 8)];
        APPLY4(LB, 0);                       // wires 0..3
        #pragma unroll
        for (int r = 0; r < APT; ++r)        // W3: same addresses as R3
            *(v2f*)&sh[a3 ^ wmix(r << 8)] = av[r];
        __syncthreads();

        #pragma unroll
        for (int r = 0; r < APT; ++r)        // Rsigma: CNOT ring, back to O1
            av[r] = *(const v2f*)&sh[aS ^ wmix(sigma_c(r))];
        __syncthreads();                     // anti-dep before next layer's W1
    }

    // ---- Z expectations (state in O1 ownership) ----
    float S = 0.f, a8 = 0.f, a9 = 0.f, a10 = 0.f, a11 = 0.f;
    #pragma unroll
    for (int r = 0; r < APT; ++r) {
        const float pr = av[r].x * av[r].x + av[r].y * av[r].y;
        S += pr;
        a8  += (r & 8) ? -pr : pr;
        a9  += (r & 4) ? -pr : pr;
        a10 += (r & 2) ? -pr : pr;
        a11 += (r & 1) ? -pr : pr;
    }
    float vals[NQ];
    #pragma unroll
    for (int w = 0; w < 8; ++w)
        vals[w] = ((tid >> (7 - w)) & 1) ? -S : S;
    vals[8] = a8; vals[9] = a9; vals[10] = a10; vals[11] = a11;
    #pragma unroll
    for (int m = 1; m <= 32; m <<= 1) {
        #pragma unroll
        for (int w = 0; w < NQ; ++w) vals[w] += __shfl_xor(vals[w], m);
    }
    if (lane == 0) {
        #pragma unroll
        for (int w = 0; w < NQ; ++w) red[wv * NQ + w] = vals[w];
    }
    __syncthreads();
    if (tid < NQ)
        red[48 + tid] = red[tid] + red[NQ + tid] + red[2 * NQ + tid] + red[3 * NQ + tid];
    __syncthreads();
    if (tid < NQ) {
        float v = db[tid];
        #pragma unroll
        for (int w = 0; w < NQ; ++w) v += red[48 + w] * dw[w * NQ + tid];
        out[s * NQ + tid] = tanhf(v);
    }
}

extern "C" void kernel_launch(void* const* d_in, const int* in_sizes, int n_in,
                              void* d_out, int out_size, void* d_ws, size_t ws_size,
                              hipStream_t stream) {
    const float* x  = (const float*)d_in[0];
    const float* qw = (const float*)d_in[1];
    const float* dw = (const float*)d_in[2];
    const float* db = (const float*)d_in[3];
    float* out   = (float*)d_out;
    float* gates = (float*)d_ws;            // 48*8 floats = 1536 B
    int batch = in_sizes[0] / NQ;
    gate_kernel<<<1, 64, 0, stream>>>(qw, gates);
    qsim_kernel<<<batch, BLK, 0, stream>>>(x, gates, dw, db, out);
}